// Round 12
// baseline (312.167 us; speedup 1.0000x reference)
//
#include <hip/hip_runtime.h>
#include <hip/hip_bf16.h>

// Problem constants (from reference)
#define B 16
#define C 128
#define H 192
#define W 192
#define HID 32
#define K 2
#define PLANE (H*W)           // 36864
#define NPLANES (B*C)         // 2048

// conv tiling (R8 proven structure)
#define TBLK 384              // threads per block (6 waves)
#define TROWS 32              // output rows per conv tile
#define SROWS 34              // staged rows (with halo)
#define LDST 196              // LDS row stride in floats (49 float4)
#define SEGS (H / TROWS)      // 6 conv tiles per plane

// persistent work-stealing task queue
#define NPOOL   NPLANES                 // 2048 pool tasks
#define NSEL    B                       // 16 selector tasks
#define NCONV   (NPLANES * SEGS)        // 12288 conv tasks
#define NTASKS  (NPOOL + NSEL + NCONV)  // 14352
#define GRID    1280                    // 5 blocks/CU x 256 CU (co-resident)

#define AGENT __HIP_MEMORY_SCOPE_AGENT

typedef float floatx4 __attribute__((ext_vector_type(4)));

// Persistent fused kernel. Tasks in order: pool planes, selector samples,
// conv tiles. Work-stealing via device atomic counter. Cross-block
// producer->consumer via agent-scope atomic stores + release/acquire flags
// (done[s]: 128 pool planes of sample s complete; selDone[s]: cw ready).
// Deadlock-free under ANY dispatch order: incomplete pool/selector tasks
// are always held by RUNNING blocks, so spinning conv blocks always make
// progress. Overlaps the read-only pool stream with conv's mixed stream
// (removes the 44 us of idle write bus of the sequential structure).
__global__ __launch_bounds__(TBLK) void persist_kernel(
        const float* __restrict__ x,
        const float* __restrict__ w1, const float* __restrict__ b1,
        const float* __restrict__ w2, const float* __restrict__ b2,
        const float* __restrict__ wb, const float* __restrict__ bias,
        unsigned int* __restrict__ ctr,
        unsigned int* __restrict__ done,
        unsigned int* __restrict__ selDone,
        float* __restrict__ pooled,
        float* __restrict__ cwA,
        float* __restrict__ out) {
    const int tid = threadIdx.x;

    __shared__ float lds[SROWS * LDST];   // conv tile / pool red / selector scratch
    __shared__ float sw[12];              // conv combined weights
    __shared__ int   sTask;

    for (;;) {
        if (tid == 0) sTask = (int)atomicAdd(ctr, 1u);
        __syncthreads();
        const int t = sTask;
        if (t >= NTASKS) return;

        if (t < NPOOL) {
            // ---------------- POOL task: mean of plane t ----------------
            const int p = t;
            const float4* px4 = (const float4*)(x + (size_t)p * PLANE);  // 9216 vec4
            float s = 0.f;
            #pragma unroll
            for (int it = 0; it < PLANE / 4 / TBLK; ++it) {   // 24 exact
                float4 v = px4[tid + it * TBLK];
                s += v.x + v.y + v.z + v.w;
            }
            for (int off = 32; off; off >>= 1) s += __shfl_down(s, off, 64);
            const int lane = tid & 63, wid = tid >> 6;
            if (lane == 0) lds[wid] = s;
            __syncthreads();
            if (tid == 0) {
                float m = (lds[0] + lds[1] + lds[2] + lds[3] + lds[4] + lds[5])
                          * (1.0f / (float)PLANE);
                __hip_atomic_store(&pooled[p], m, __ATOMIC_RELAXED, AGENT);
                __hip_atomic_fetch_add(&done[p >> 7], 1u, __ATOMIC_RELEASE, AGENT);
            }
        } else if (t < NPOOL + NSEL) {
            // ---------------- SELECTOR task: sample s ----------------
            const int s = t - NPOOL;
            if (tid == 0) {
                while (__hip_atomic_load(&done[s], __ATOMIC_ACQUIRE, AGENT) < 128u)
                    __builtin_amdgcn_s_sleep(32);
            }
            __syncthreads();
            float* sh   = lds;        // [32]
            float* sAtt = lds + 64;   // [2]
            if (tid < HID) {
                float acc = b1[tid];
                const float* wj = w1 + tid * C;
                #pragma unroll 8
                for (int cc = 0; cc < C; ++cc) {
                    float pv = __hip_atomic_load(&pooled[s * C + cc], __ATOMIC_RELAXED, AGENT);
                    acc = fmaf(pv, wj[cc], acc);
                }
                sh[tid] = fmaxf(acc, 0.f);
            }
            __syncthreads();
            if (tid < K) {
                float acc = b2[tid];
                const float* wk = w2 + tid * HID;
                #pragma unroll
                for (int j = 0; j < HID; ++j) acc = fmaf(sh[j], wk[j], acc);
                sAtt[tid] = acc;
            }
            __syncthreads();
            if (tid == 0) {
                const float a0 = sAtt[0], a1 = sAtt[1];
                const float m = fmaxf(a0, a1);
                const float e0 = __expf(a0 - m), e1 = __expf(a1 - m);
                const float inv = 1.f / (e0 + e1);
                sAtt[0] = e0 * inv;
                sAtt[1] = e1 * inv;
            }
            __syncthreads();
            const float a0 = sAtt[0], a1 = sAtt[1];
            for (int i = tid; i < C * 9; i += TBLK) {
                float v = a0 * wb[i] + a1 * wb[C * 9 + i];
                __hip_atomic_store(&cwA[s * C * 9 + i], v, __ATOMIC_RELAXED, AGENT);
            }
            __syncthreads();
            if (tid == 0)
                __hip_atomic_store(&selDone[s], 1u, __ATOMIC_RELEASE, AGENT);
        } else {
            // ---------------- CONV task: tile (plane, seg) ----------------
            const int tt    = t - NPOOL - NSEL;
            const int plane = tt / SEGS;
            const int seg   = tt % SEGS;
            const int c     = plane & (C - 1);
            const int s     = plane >> 7;
            const int y0    = seg * TROWS;

            // stage 34 rows x 48 float4 into LDS (coalesced, R8 structure)
            const float4* px4 = (const float4*)(x + (size_t)plane * PLANE);
            float4* lds4 = (float4*)lds;
            #pragma unroll
            for (int k = 0; k < 5; ++k) {
                const int idx = tid + k * TBLK;          // 0..1631
                if (idx < SROWS * 48) {
                    const int row  = idx / 48;
                    const int col4 = idx % 48;
                    const int gRow = y0 - 1 + row;
                    float4 v = make_float4(0.f, 0.f, 0.f, 0.f);
                    if (gRow >= 0 && gRow < H) v = px4[gRow * 48 + col4];
                    lds4[row * 49 + col4] = v;
                }
            }
            // spin for this sample's weights (overlaps staging latency)
            if (tid == 0) {
                while (!__hip_atomic_load(&selDone[s], __ATOMIC_ACQUIRE, AGENT))
                    __builtin_amdgcn_s_sleep(16);
            }
            __syncthreads();   // tile staged + flag acquired
            if (tid < 9)
                sw[tid] = __hip_atomic_load(&cwA[(size_t)s * C * 9 + c * 9 + tid],
                                            __ATOMIC_RELAXED, AGENT);
            __syncthreads();

            const float w00 = sw[0], w01 = sw[1], w02 = sw[2];
            const float w10 = sw[3], w11 = sw[4], w12 = sw[5];
            const float w20 = sw[6], w21 = sw[7], w22 = sw[8];
            const float bv = bias[c];

            const int xq   = tid % 48;
            const int band = tid / 48;      // 0..7
            const int x0   = xq * 4;

            float acc[4][4];
            #pragma unroll
            for (int j = 0; j < 4; ++j) {
                acc[j][0] = bv; acc[j][1] = bv; acc[j][2] = bv; acc[j][3] = bv;
            }

            #pragma unroll
            for (int i = 0; i < 6; ++i) {
                const int sr = band * 4 + i;
                const float* lr = lds + sr * LDST;
                const floatx4 cur = *(const floatx4*)(lr + x0);
                const float v0 = (xq > 0)  ? lr[x0 - 1] : 0.f;
                const float v5 = (xq < 47) ? lr[x0 + 4] : 0.f;
                const float v1 = cur.x, v2 = cur.y, v3 = cur.z, v4 = cur.w;

                if (i < 4) {
                    acc[i][0] = fmaf(w00, v0, fmaf(w01, v1, fmaf(w02, v2, acc[i][0])));
                    acc[i][1] = fmaf(w00, v1, fmaf(w01, v2, fmaf(w02, v3, acc[i][1])));
                    acc[i][2] = fmaf(w00, v2, fmaf(w01, v3, fmaf(w02, v4, acc[i][2])));
                    acc[i][3] = fmaf(w00, v3, fmaf(w01, v4, fmaf(w02, v5, acc[i][3])));
                }
                if (i >= 1 && i <= 4) {
                    acc[i-1][0] = fmaf(w10, v0, fmaf(w11, v1, fmaf(w12, v2, acc[i-1][0])));
                    acc[i-1][1] = fmaf(w10, v1, fmaf(w11, v2, fmaf(w12, v3, acc[i-1][1])));
                    acc[i-1][2] = fmaf(w10, v2, fmaf(w11, v3, fmaf(w12, v4, acc[i-1][2])));
                    acc[i-1][3] = fmaf(w10, v3, fmaf(w11, v4, fmaf(w12, v5, acc[i-1][3])));
                }
                if (i >= 2) {
                    acc[i-2][0] = fmaf(w20, v0, fmaf(w21, v1, fmaf(w22, v2, acc[i-2][0])));
                    acc[i-2][1] = fmaf(w20, v1, fmaf(w21, v2, fmaf(w22, v3, acc[i-2][1])));
                    acc[i-2][2] = fmaf(w20, v2, fmaf(w21, v3, fmaf(w22, v4, acc[i-2][2])));
                    acc[i-2][3] = fmaf(w20, v3, fmaf(w21, v4, fmaf(w22, v5, acc[i-2][3])));
                }
            }

            float* po = out + (size_t)plane * PLANE + (y0 + band * 4) * W + x0;
            #pragma unroll
            for (int j = 0; j < 4; ++j) {
                floatx4 o = { acc[j][0], acc[j][1], acc[j][2], acc[j][3] };
                __builtin_nontemporal_store(o, (floatx4*)(po + j * W));
            }
        }
        __syncthreads();   // LDS reuse across loop iterations
    }
}

extern "C" void kernel_launch(void* const* d_in, const int* in_sizes, int n_in,
                              void* d_out, int out_size, void* d_ws, size_t ws_size,
                              hipStream_t stream) {
    const float* x    = (const float*)d_in[0];
    const float* w1   = (const float*)d_in[1];
    const float* b1   = (const float*)d_in[2];
    const float* w2   = (const float*)d_in[3];
    const float* b2   = (const float*)d_in[4];
    const float* wb   = (const float*)d_in[5];
    const float* bias = (const float*)d_in[6];
    float* out = (float*)d_out;

    // ws layout (all zeroed each call; deterministic)
    unsigned int* ctr     = (unsigned int*)d_ws;   // [0]   task counter
    unsigned int* done    = ctr + 32;              // [16]  per-sample pool count
    unsigned int* selDone = ctr + 64;              // [16]  per-sample cw ready
    float* pooled = (float*)(ctr + 256);           // [2048]
    float* cwA    = pooled + NPLANES;              // [2048*9]

    const size_t zbytes = (256 + NPLANES + NPLANES * 9) * sizeof(float);
    hipMemsetAsync(d_ws, 0, zbytes, stream);

    persist_kernel<<<GRID, TBLK, 0, stream>>>(x, w1, b1, w2, b2, wb, bias,
                                              ctr, done, selDone, pooled, cwA, out);
}

// Round 13
// 174.843 us; speedup vs baseline: 1.7854x; 1.7854x over previous
//
#include <hip/hip_runtime.h>
#include <hip/hip_bf16.h>

// Problem constants (from reference)
#define B 16
#define C 128
#define H 192
#define W 192
#define HID 32
#define K 2
#define PLANE (H*W)           // 36864
#define NPLANES (B*C)         // 2048

// conv tiling (R8 proven structure)
#define TBLK 384              // threads per conv block (6 waves)
#define TROWS 32              // output rows per block
#define SROWS 34              // staged rows (with halo)
#define LDST 196              // LDS row stride in floats (49 float4)
#define SEGS (H / TROWS)      // 6 blocks per plane

typedef float floatx4 __attribute__((ext_vector_type(4)));

// ---------------- Kernel 1: global average pool per (b,c) plane ----------------
__global__ __launch_bounds__(256) void pool_kernel(const float* __restrict__ x,
                                                   float* __restrict__ pooled) {
    const int plane = blockIdx.x;  // b*C + c
    const float4* px4 = (const float4*)(x + (size_t)plane * PLANE);  // 9216 float4
    float s = 0.f;
    for (int i = threadIdx.x; i < PLANE / 4; i += 256) {
        float4 v = px4[i];
        s += v.x + v.y + v.z + v.w;
    }
    for (int off = 32; off; off >>= 1) s += __shfl_down(s, off, 64);
    __shared__ float wsum[4];
    const int lane = threadIdx.x & 63, wid = threadIdx.x >> 6;
    if (lane == 0) wsum[wid] = s;
    __syncthreads();
    if (threadIdx.x == 0) {
        pooled[plane] = (wsum[0] + wsum[1] + wsum[2] + wsum[3]) * (1.0f / (float)PLANE);
    }
}

// ---------------- Kernel 2: selector MLP + softmax + weight combine ----------------
__global__ __launch_bounds__(512) void selector_kernel(const float* __restrict__ pooled,
                                                       const float* __restrict__ w1,
                                                       const float* __restrict__ b1,
                                                       const float* __restrict__ w2,
                                                       const float* __restrict__ b2,
                                                       const float* __restrict__ wb,
                                                       float* __restrict__ cw) {
    __shared__ float h[B][HID];
    __shared__ float attn[B][K];
    const int tid = threadIdx.x;

    {
        const int b = tid >> 5, j = tid & 31;
        float s = b1[j];
        const float* pb = pooled + b * C;
        const float* wj = w1 + j * C;
        #pragma unroll 8
        for (int c = 0; c < C; ++c) s += pb[c] * wj[c];
        h[b][j] = fmaxf(s, 0.f);
    }
    __syncthreads();
    if (tid < B * K) {
        const int b = tid >> 1, k = tid & 1;
        float s = b2[k];
        const float* wk = w2 + k * HID;
        #pragma unroll
        for (int j = 0; j < HID; ++j) s += h[b][j] * wk[j];
        attn[b][k] = s;
    }
    __syncthreads();
    if (tid < B) {
        const float a0 = attn[tid][0], a1 = attn[tid][1];
        const float m = fmaxf(a0, a1);
        const float e0 = __expf(a0 - m), e1 = __expf(a1 - m);
        const float inv = 1.f / (e0 + e1);
        attn[tid][0] = e0 * inv;
        attn[tid][1] = e1 * inv;
    }
    __syncthreads();
    for (int i = tid; i < B * C * 9; i += 512) {
        const int b = i / (C * 9);
        const int ci = i % (C * 9);
        cw[i] = attn[b][0] * wb[ci] + attn[b][1] * wb[C * 9 + ci];
    }
}

// ---------------- Kernel 3: depthwise 3x3 conv (pad 1) + bias, LDS-staged ----------------
// R8 structure (each cache line probed once via coalesced LDS staging; NT
// stores). SINGLE-VARIABLE A/B vs R8: staging loads are NONTEMPORAL —
// x is read exactly once by conv (reuse lives in LDS), so L2/L3 line
// allocation for these reads is pure churn against the NT write stream.
__global__ __launch_bounds__(TBLK) void conv_kernel(const float* __restrict__ x,
                                                    const float* __restrict__ cw,
                                                    const float* __restrict__ bias,
                                                    float* __restrict__ out) {
    __shared__ float lds[SROWS * LDST];

    const int bid   = blockIdx.x;
    const int plane = bid / SEGS;          // forward, block-uniform
    const int seg   = bid % SEGS;
    const int tid   = threadIdx.x;
    const int c     = plane & (C - 1);
    const int y0    = seg * TROWS;

    const float* w = cw + plane * 9;
    const float w00 = w[0], w01 = w[1], w02 = w[2];
    const float w10 = w[3], w11 = w[4], w12 = w[5];
    const float w20 = w[6], w21 = w[7], w22 = w[8];
    const float bv = bias[c];

    // ---- stage 34 rows x 192 cols (48 float4 per row) into LDS ----
    const floatx4* px4 = (const floatx4*)(x + (size_t)plane * PLANE);
    floatx4* lds4 = (floatx4*)lds;
    #pragma unroll
    for (int k = 0; k < 5; ++k) {
        const int idx = tid + k * TBLK;          // 0..1631 (34*48)
        if (idx < SROWS * 48) {
            const int row  = idx / 48;           // staged row
            const int col4 = idx % 48;
            const int gRow = y0 - 1 + row;       // global image row
            floatx4 v = {0.f, 0.f, 0.f, 0.f};
            if (gRow >= 0 && gRow < H)
                v = __builtin_nontemporal_load(px4 + gRow * 48 + col4);
            lds4[row * 49 + col4] = v;
        }
    }
    __syncthreads();

    // ---- compute: thread = 4-wide x 4-tall ----
    const int xq   = tid % 48;      // col strip
    const int band = tid / 48;      // 0..7 (4 rows each)
    const int x0   = xq * 4;

    float acc[4][4];
    #pragma unroll
    for (int j = 0; j < 4; ++j) {
        acc[j][0] = bv; acc[j][1] = bv; acc[j][2] = bv; acc[j][3] = bv;
    }

    #pragma unroll
    for (int i = 0; i < 6; ++i) {
        const int sr = band * 4 + i;            // staged row index
        const float* lr = lds + sr * LDST;
        const floatx4 cur = *(const floatx4*)(lr + x0);
        const float v0 = (xq > 0)  ? lr[x0 - 1] : 0.f;
        const float v5 = (xq < 47) ? lr[x0 + 4] : 0.f;
        const float v1 = cur.x, v2 = cur.y, v3 = cur.z, v4 = cur.w;

        // staged row sr: TOP tap of out j=i, MID of j=i-1, BOTTOM of j=i-2
        if (i < 4) {
            acc[i][0] = fmaf(w00, v0, fmaf(w01, v1, fmaf(w02, v2, acc[i][0])));
            acc[i][1] = fmaf(w00, v1, fmaf(w01, v2, fmaf(w02, v3, acc[i][1])));
            acc[i][2] = fmaf(w00, v2, fmaf(w01, v3, fmaf(w02, v4, acc[i][2])));
            acc[i][3] = fmaf(w00, v3, fmaf(w01, v4, fmaf(w02, v5, acc[i][3])));
        }
        if (i >= 1 && i <= 4) {
            acc[i-1][0] = fmaf(w10, v0, fmaf(w11, v1, fmaf(w12, v2, acc[i-1][0])));
            acc[i-1][1] = fmaf(w10, v1, fmaf(w11, v2, fmaf(w12, v3, acc[i-1][1])));
            acc[i-1][2] = fmaf(w10, v2, fmaf(w11, v3, fmaf(w12, v4, acc[i-1][2])));
            acc[i-1][3] = fmaf(w10, v3, fmaf(w11, v4, fmaf(w12, v5, acc[i-1][3])));
        }
        if (i >= 2) {
            acc[i-2][0] = fmaf(w20, v0, fmaf(w21, v1, fmaf(w22, v2, acc[i-2][0])));
            acc[i-2][1] = fmaf(w20, v1, fmaf(w21, v2, fmaf(w22, v3, acc[i-2][1])));
            acc[i-2][2] = fmaf(w20, v2, fmaf(w21, v3, fmaf(w22, v4, acc[i-2][2])));
            acc[i-2][3] = fmaf(w20, v3, fmaf(w21, v4, fmaf(w22, v5, acc[i-2][3])));
        }
    }

    float* po = out + (size_t)plane * PLANE + (y0 + band * 4) * W + x0;
    #pragma unroll
    for (int j = 0; j < 4; ++j) {
        floatx4 o = { acc[j][0], acc[j][1], acc[j][2], acc[j][3] };
        __builtin_nontemporal_store(o, (floatx4*)(po + j * W));
    }
}

extern "C" void kernel_launch(void* const* d_in, const int* in_sizes, int n_in,
                              void* d_out, int out_size, void* d_ws, size_t ws_size,
                              hipStream_t stream) {
    const float* x    = (const float*)d_in[0];
    const float* w1   = (const float*)d_in[1];
    const float* b1   = (const float*)d_in[2];
    const float* w2   = (const float*)d_in[3];
    const float* b2   = (const float*)d_in[4];
    const float* wb   = (const float*)d_in[5];
    const float* bias = (const float*)d_in[6];
    float* out = (float*)d_out;

    float* pooled = (float*)d_ws;          // [2048]
    float* cw     = pooled + NPLANES;      // [2048*9]

    pool_kernel<<<NPLANES, 256, 0, stream>>>(x, pooled);
    selector_kernel<<<1, 512, 0, stream>>>(pooled, w1, b1, w2, b2, wb, cw);
    conv_kernel<<<NPLANES * SEGS, TBLK, 0, stream>>>(x, cw, bias, out);
}

// Round 14
// 163.275 us; speedup vs baseline: 1.9119x; 1.0708x over previous
//
#include <hip/hip_runtime.h>
#include <hip/hip_bf16.h>

// Problem constants (from reference)
#define B 16
#define C 128
#define H 192
#define W 192
#define HID 32
#define K 2
#define PLANE (H*W)           // 36864
#define NPLANES (B*C)         // 2048

// conv tiling
#define TBLK 384              // threads per conv block (6 waves)
#define TROWS 32              // output rows per block
#define SROWS 34              // staged rows (with halo)
#define LDST 196              // LDS row stride in floats (49 float4)
#define SEGS (H / TROWS)      // 6 blocks per plane

typedef float floatx4 __attribute__((ext_vector_type(4)));

// ---------------- Kernel 1: global average pool per (b,c) plane ----------------
__global__ __launch_bounds__(256) void pool_kernel(const float* __restrict__ x,
                                                   float* __restrict__ pooled) {
    const int plane = blockIdx.x;  // b*C + c
    const float4* px4 = (const float4*)(x + (size_t)plane * PLANE);  // 9216 float4
    float s = 0.f;
    for (int i = threadIdx.x; i < PLANE / 4; i += 256) {
        float4 v = px4[i];
        s += v.x + v.y + v.z + v.w;
    }
    for (int off = 32; off; off >>= 1) s += __shfl_down(s, off, 64);
    __shared__ float wsum[4];
    const int lane = threadIdx.x & 63, wid = threadIdx.x >> 6;
    if (lane == 0) wsum[wid] = s;
    __syncthreads();
    if (threadIdx.x == 0) {
        pooled[plane] = (wsum[0] + wsum[1] + wsum[2] + wsum[3]) * (1.0f / (float)PLANE);
    }
}

// ---------------- Kernel 2: selector MLP + softmax + weight combine ----------------
__global__ __launch_bounds__(512) void selector_kernel(const float* __restrict__ pooled,
                                                       const float* __restrict__ w1,
                                                       const float* __restrict__ b1,
                                                       const float* __restrict__ w2,
                                                       const float* __restrict__ b2,
                                                       const float* __restrict__ wb,
                                                       float* __restrict__ cw) {
    __shared__ float h[B][HID];
    __shared__ float attn[B][K];
    const int tid = threadIdx.x;

    {
        const int b = tid >> 5, j = tid & 31;
        float s = b1[j];
        const float* pb = pooled + b * C;
        const float* wj = w1 + j * C;
        #pragma unroll 8
        for (int c = 0; c < C; ++c) s += pb[c] * wj[c];
        h[b][j] = fmaxf(s, 0.f);
    }
    __syncthreads();
    if (tid < B * K) {
        const int b = tid >> 1, k = tid & 1;
        float s = b2[k];
        const float* wk = w2 + k * HID;
        #pragma unroll
        for (int j = 0; j < HID; ++j) s += h[b][j] * wk[j];
        attn[b][k] = s;
    }
    __syncthreads();
    if (tid < B) {
        const float a0 = attn[tid][0], a1 = attn[tid][1];
        const float m = fmaxf(a0, a1);
        const float e0 = __expf(a0 - m), e1 = __expf(a1 - m);
        const float inv = 1.f / (e0 + e1);
        attn[tid][0] = e0 * inv;
        attn[tid][1] = e1 * inv;
    }
    __syncthreads();
    for (int i = tid; i < B * C * 9; i += 512) {
        const int b = i / (C * 9);
        const int ci = i % (C * 9);
        cw[i] = attn[b][0] * wb[ci] + attn[b][1] * wb[C * 9 + ci];
    }
}

// ---------------- Kernel 3: depthwise 3x3 conv (pad 1) + bias, LDS-staged ----------------
// FINAL (R8): block stages a 34x192 input tile into LDS once via coalesced
// plain dwordx4 loads (each cache line probed exactly once -> broke the
// ~3 TB/s L1 tag-lookup wall of register-tiled variants), computes 32
// output rows from LDS, NT dwordx4 stores (A/B-proven vs plain: 163 vs 182;
// NT staging loads A/B-proven worse: 175). L3-placement and overlap
// restructurings all null/regressive -> conv runs at the fabric's mixed
// R+W stream rate (~5.25 TB/s), which is this op's practical roofline.
__global__ __launch_bounds__(TBLK) void conv_kernel(const float* __restrict__ x,
                                                    const float* __restrict__ cw,
                                                    const float* __restrict__ bias,
                                                    float* __restrict__ out) {
    __shared__ float lds[SROWS * LDST];

    const int bid   = blockIdx.x;
    const int plane = bid / SEGS;          // forward, block-uniform
    const int seg   = bid % SEGS;
    const int tid   = threadIdx.x;
    const int c     = plane & (C - 1);
    const int y0    = seg * TROWS;

    const float* w = cw + plane * 9;
    const float w00 = w[0], w01 = w[1], w02 = w[2];
    const float w10 = w[3], w11 = w[4], w12 = w[5];
    const float w20 = w[6], w21 = w[7], w22 = w[8];
    const float bv = bias[c];

    // ---- stage 34 rows x 192 cols (48 float4 per row) into LDS ----
    const float4* px4 = (const float4*)(x + (size_t)plane * PLANE);
    float4* lds4 = (float4*)lds;
    #pragma unroll
    for (int k = 0; k < 5; ++k) {
        const int idx = tid + k * TBLK;          // 0..1631 (34*48)
        if (idx < SROWS * 48) {
            const int row  = idx / 48;           // staged row
            const int col4 = idx % 48;
            const int gRow = y0 - 1 + row;       // global image row
            float4 v = make_float4(0.f, 0.f, 0.f, 0.f);
            if (gRow >= 0 && gRow < H) v = px4[gRow * 48 + col4];
            lds4[row * 49 + col4] = v;
        }
    }
    __syncthreads();

    // ---- compute: thread = 4-wide x 4-tall ----
    const int xq   = tid % 48;      // col strip
    const int band = tid / 48;      // 0..7 (4 rows each)
    const int x0   = xq * 4;

    float acc[4][4];
    #pragma unroll
    for (int j = 0; j < 4; ++j) {
        acc[j][0] = bv; acc[j][1] = bv; acc[j][2] = bv; acc[j][3] = bv;
    }

    #pragma unroll
    for (int i = 0; i < 6; ++i) {
        const int sr = band * 4 + i;            // staged row index
        const float* lr = lds + sr * LDST;
        const floatx4 cur = *(const floatx4*)(lr + x0);
        const float v0 = (xq > 0)  ? lr[x0 - 1] : 0.f;
        const float v5 = (xq < 47) ? lr[x0 + 4] : 0.f;
        const float v1 = cur.x, v2 = cur.y, v3 = cur.z, v4 = cur.w;

        // staged row sr: TOP tap of out j=i, MID of j=i-1, BOTTOM of j=i-2
        if (i < 4) {
            acc[i][0] = fmaf(w00, v0, fmaf(w01, v1, fmaf(w02, v2, acc[i][0])));
            acc[i][1] = fmaf(w00, v1, fmaf(w01, v2, fmaf(w02, v3, acc[i][1])));
            acc[i][2] = fmaf(w00, v2, fmaf(w01, v3, fmaf(w02, v4, acc[i][2])));
            acc[i][3] = fmaf(w00, v3, fmaf(w01, v4, fmaf(w02, v5, acc[i][3])));
        }
        if (i >= 1 && i <= 4) {
            acc[i-1][0] = fmaf(w10, v0, fmaf(w11, v1, fmaf(w12, v2, acc[i-1][0])));
            acc[i-1][1] = fmaf(w10, v1, fmaf(w11, v2, fmaf(w12, v3, acc[i-1][1])));
            acc[i-1][2] = fmaf(w10, v2, fmaf(w11, v3, fmaf(w12, v4, acc[i-1][2])));
            acc[i-1][3] = fmaf(w10, v3, fmaf(w11, v4, fmaf(w12, v5, acc[i-1][3])));
        }
        if (i >= 2) {
            acc[i-2][0] = fmaf(w20, v0, fmaf(w21, v1, fmaf(w22, v2, acc[i-2][0])));
            acc[i-2][1] = fmaf(w20, v1, fmaf(w21, v2, fmaf(w22, v3, acc[i-2][1])));
            acc[i-2][2] = fmaf(w20, v2, fmaf(w21, v3, fmaf(w22, v4, acc[i-2][2])));
            acc[i-2][3] = fmaf(w20, v3, fmaf(w21, v4, fmaf(w22, v5, acc[i-2][3])));
        }
    }

    float* po = out + (size_t)plane * PLANE + (y0 + band * 4) * W + x0;
    #pragma unroll
    for (int j = 0; j < 4; ++j) {
        floatx4 o = { acc[j][0], acc[j][1], acc[j][2], acc[j][3] };
        __builtin_nontemporal_store(o, (floatx4*)(po + j * W));
    }
}

extern "C" void kernel_launch(void* const* d_in, const int* in_sizes, int n_in,
                              void* d_out, int out_size, void* d_ws, size_t ws_size,
                              hipStream_t stream) {
    const float* x    = (const float*)d_in[0];
    const float* w1   = (const float*)d_in[1];
    const float* b1   = (const float*)d_in[2];
    const float* w2   = (const float*)d_in[3];
    const float* b2   = (const float*)d_in[4];
    const float* wb   = (const float*)d_in[5];
    const float* bias = (const float*)d_in[6];
    float* out = (float*)d_out;

    float* pooled = (float*)d_ws;          // [2048]
    float* cw     = pooled + NPLANES;      // [2048*9]

    pool_kernel<<<NPLANES, 256, 0, stream>>>(x, pooled);
    selector_kernel<<<1, 512, 0, stream>>>(pooled, w1, b1, w2, b2, wb, cw);
    conv_kernel<<<NPLANES * SEGS, TBLK, 0, stream>>>(x, cw, bias, out);
}